// Round 14
// baseline (893.789 us; speedup 1.0000x reference)
//
#include <hip/hip_runtime.h>
#include <math.h>

// ---------------- problem constants ----------------
#define TLEN   64000
#define ECH    256
#define DCH    512
#define NBLK   2
#define NLAY   6
#define FKC    20
#define STRIDE_ 10
#define TC     6403            // encoder output length
#define NS     12928           // padded row count = 101*128 (n = b*TC + tc)
#define NTILE  101             // NS / 128
#define EPSV   1e-5f

typedef __attribute__((ext_vector_type(8))) short          s8v;
typedef __attribute__((ext_vector_type(4))) float          f4v;
typedef __attribute__((ext_vector_type(4))) unsigned short u4v;
typedef __attribute__((ext_vector_type(8))) unsigned short u8v;

__device__ __forceinline__ unsigned short f2bf(float f) {
    union { float f; unsigned u; } v; v.f = f;
    unsigned r = v.u + 0x7FFFu + ((v.u >> 16) & 1u);   // RNE
    return (unsigned short)(r >> 16);
}
__device__ __forceinline__ float bf2f(unsigned short h) {
    union { unsigned u; float f; } v; v.u = ((unsigned)h) << 16; return v.f;
}

// =====================================================================
// wcvt: weights fp32->bf16 (verified) + NEW: pack dw params
// dwp[li*512+d][8] = {w0,w1,w2,bd, sc,mn,bt,al}  (same fp32 math as dw_k)
// =====================================================================
#define NWQ (12*512*256/4)      // float4 count per tensor = 393216
#define NB0 (2*NWQ/256)         // 3072 blocks for weight convert
__global__ __launch_bounds__(256)
void wcvt_k(const float* __restrict__ w1, const float* __restrict__ w2,
            const float* __restrict__ wd, const float* __restrict__ bd,
            const float* __restrict__ a2, const float* __restrict__ g2,
            const float* __restrict__ be2, const float* __restrict__ m2,
            const float* __restrict__ v2,
            unsigned short* __restrict__ w1b, unsigned short* __restrict__ w2b,
            float* __restrict__ dwp)
{
    const int bx = blockIdx.x;
    const int t  = threadIdx.x;
    if (bx < NB0) {
        int i = bx * 256 + t;
        if (i < NWQ) {
            float4 v = ((const float4*)w1)[i];
            u4v o = { f2bf(v.x), f2bf(v.y), f2bf(v.z), f2bf(v.w) };
            ((u4v*)w1b)[i] = o;
        } else {
            int j = i - NWQ;
            float4 v = ((const float4*)w2)[j];
            u4v o = { f2bf(v.x), f2bf(v.y), f2bf(v.z), f2bf(v.w) };
            ((u4v*)w2b)[j] = o;
        }
    } else {
        int idx = (bx - NB0) * 256 + t;          // 0..6143 (12 layers x 512 d)
        int li = idx >> 9, d = idx & 511;
        float w0  = wd[li * 1536 + d * 3 + 0];
        float w1v = wd[li * 1536 + d * 3 + 1];
        float w2v = wd[li * 1536 + d * 3 + 2];
        float bdv = bd[li * 512 + d];
        float sc  = g2[li * 512 + d] / sqrtf(v2[li * 512 + d] + EPSV);
        float mn  = m2[li * 512 + d];
        float bt  = be2[li * 512 + d];
        float al  = a2[li];
        float* o = dwp + (size_t)idx * 8;
        o[0] = w0; o[1] = w1v; o[2] = w2v; o[3] = bdv;
        o[4] = sc; o[5] = mn;  o[6] = bt;  o[7] = al;
    }
}

// =====================================================================
// Encoder -> bf16 [N][E] directly (verified)
// =====================================================================
__global__ __launch_bounds__(256)
void encoder_k(const float* __restrict__ x, const float* __restrict__ ew,
               const float* __restrict__ eb,
               unsigned short* __restrict__ EncB, unsigned short* __restrict__ Hb)
{
    __shared__ float xs[660];
    const int bx  = blockIdx.x;      // 0..100
    const int b   = blockIdx.y;      // 0..1
    const int tc0 = bx * 64;
    const int base_g = tc0 * STRIDE_ - FKC;
    for (int i = threadIdx.x; i < 660; i += 256) {
        int idx = base_g + i;
        xs[i] = (idx >= 0 && idx < TLEN) ? x[b * TLEN + idx] : 0.f;
    }
    __syncthreads();

    const int e = threadIdx.x;
    float w[20];
    #pragma unroll
    for (int q = 0; q < 5; ++q) {
        float4 v = *(const float4*)&ew[e * 20 + q * 4];
        w[q*4+0] = v.x; w[q*4+1] = v.y; w[q*4+2] = v.z; w[q*4+3] = v.w;
    }
    const float bz = eb[e];
    const int jmax = (TC - tc0 < 64) ? (TC - tc0) : 64;
    for (int j = 0; j < jmax; ++j) {
        const float* xp = &xs[j * 10];
        float acc = bz;
        #pragma unroll
        for (int k = 0; k < 20; ++k) acc = fmaf(xp[k], w[k], acc);
        unsigned short hv = f2bf(acc);
        size_t o = (size_t)(b * TC + tc0 + j) * 256 + e;
        EncB[o] = hv;
        Hb[o]   = hv;
    }
}

// =====================================================================
// conv1 GEMM (r13 VERBATIM, verified): 128x128, gload_lds, 2-phase dbuf
//   acc[n][m] = sum_k W[m][k] * Act[n][k];  EPI0: bias+PReLU+BN
// =====================================================================
template<int KD, int MOUT>
__global__ __launch_bounds__(256)
void gemm_bf16_k(const unsigned short* __restrict__ Wb,
                 const unsigned short* __restrict__ Act,
                 unsigned short* __restrict__ OutB,
                 const float* __restrict__ bias,
                 const float* __restrict__ alpha,
                 const float* __restrict__ gamma,
                 const float* __restrict__ beta,
                 const float* __restrict__ mean,
                 const float* __restrict__ var)
{
    __shared__ short At[2 * 128 * 32];
    __shared__ short Bt[2 * 128 * 32];

    const int t    = threadIdx.x;
    const int lane = t & 63;
    const int wid  = t >> 6;
    const int wm   = wid >> 1, wn = wid & 1;
    const int r16  = lane & 15, g = lane >> 4;
    const int mb   = blockIdx.y * 128;
    const int nb   = blockIdx.x * 128;

    f4v acc[4][4];
    #pragma unroll
    for (int a = 0; a < 4; ++a)
        #pragma unroll
        for (int c = 0; c < 4; ++c)
            acc[a][c] = (f4v){0.f, 0.f, 0.f, 0.f};

    const char* gA = (const char*)Wb;
    const char* gB = (const char*)Act;
    char* lA = (char*)At;
    char* lB = (char*)Bt;

    auto stage = [&](int buf, int k0) {
        #pragma unroll
        for (int i = 0; i < 2; ++i) {
            int ch = i * 256 + t;
            const char* srcA = gA + ((size_t)(mb + (ch >> 2)) * KD + k0) * 2 + (ch & 3) * 16;
            __builtin_amdgcn_global_load_lds(
                (const __attribute__((address_space(1))) void*)srcA,
                (__attribute__((address_space(3))) void*)(lA + buf * 8192 + i * 4096 + wid * 1024),
                16, 0, 0);
            const char* srcB = gB + ((size_t)(nb + (ch >> 2)) * KD + k0) * 2 + (ch & 3) * 16;
            __builtin_amdgcn_global_load_lds(
                (const __attribute__((address_space(1))) void*)srcB,
                (__attribute__((address_space(3))) void*)(lB + buf * 8192 + i * 4096 + wid * 1024),
                16, 0, 0);
        }
    };

    constexpr int NSTEP = KD / 32;
    stage(0, 0);
    __syncthreads();

    for (int s = 0; s < NSTEP; ++s) {
        const int cur = s & 1;
        if (s + 1 < NSTEP) stage(cur ^ 1, (s + 1) * 32);

        const short* cA = At + cur * 128 * 32;
        const short* cB = Bt + cur * 128 * 32;
        s8v av[4], bv[4];
        #pragma unroll
        for (int f = 0; f < 4; ++f) {
            av[f] = *(const s8v*)&cA[(wm * 64 + f * 16 + r16) * 32 + g * 8];
            bv[f] = *(const s8v*)&cB[(wn * 64 + f * 16 + r16) * 32 + g * 8];
        }
        #pragma unroll
        for (int fm = 0; fm < 4; ++fm)
            #pragma unroll
            for (int fn = 0; fn < 4; ++fn)
                acc[fm][fn] = __builtin_amdgcn_mfma_f32_16x16x32_bf16(
                    av[fm], bv[fn], acc[fm][fn], 0, 0, 0);

        __syncthreads();
    }

    const float al = alpha[0];
    #pragma unroll
    for (int fm = 0; fm < 4; ++fm) {
        const int mbase = mb + wm * 64 + fm * 16 + g * 4;
        float4 b4 = *(const float4*)&bias[mbase];
        float bb[4] = { b4.x, b4.y, b4.z, b4.w };
        float4 g4  = *(const float4*)&gamma[mbase];
        float4 v4  = *(const float4*)&var[mbase];
        float4 m4  = *(const float4*)&mean[mbase];
        float4 be4 = *(const float4*)&beta[mbase];
        float sc[4] = { g4.x / sqrtf(v4.x + EPSV), g4.y / sqrtf(v4.y + EPSV),
                        g4.z / sqrtf(v4.z + EPSV), g4.w / sqrtf(v4.w + EPSV) };
        float mn[4] = { m4.x, m4.y, m4.z, m4.w };
        float bt[4] = { be4.x, be4.y, be4.z, be4.w };
        #pragma unroll
        for (int fn = 0; fn < 4; ++fn) {
            const int n = nb + wn * 64 + fn * 16 + r16;
            f4v a = acc[fm][fn];
            u4v ro;
            #pragma unroll
            for (int r = 0; r < 4; ++r) {
                float v = a[r] + bb[r];
                v = (v > 0.f) ? v : al * v;
                v = (v - mn[r]) * sc[r] + bt[r];
                ro[r] = f2bf(v);
            }
            *(u4v*)&OutB[(size_t)n * MOUT + mbase] = ro;
        }
    }
}

// =====================================================================
// FUSED conv2 GEMM: B[n][k] = dw(P)[n][k] computed during staging.
// r9-verified reg-staged skeleton (LROW=40, 1-step prefetch).
// EPI 1: bias -> Hb2 | 2: bias+resid -> Hb (in-place safe)
//     | 3: bias+resid, then mask: Mb = EncB * sigmoid(bf16(h))
// dw math bit-identical to old dw_k (params pre-packed in dwp).
// =====================================================================
#define LROW2 40

template<int EPI>
__global__ __launch_bounds__(256)
void gemm_dw_k(const unsigned short* __restrict__ Wb,
               const unsigned short* __restrict__ Pin,
               const float* __restrict__ dwpL,
               unsigned short* __restrict__ OutB,
               const float* __restrict__ bias,
               const unsigned short* __restrict__ Resid,
               const unsigned short* __restrict__ EncB,
               int dil)
{
    constexpr int KD   = DCH;    // 512
    constexpr int MOUT = ECH;    // 256
    __shared__ short At[128 * LROW2];
    __shared__ short Bt[128 * LROW2];

    const int t    = threadIdx.x;
    const int lane = t & 63;
    const int wid  = t >> 6;
    const int wm   = wid >> 1, wn = wid & 1;
    const int r16  = lane & 15, g = lane >> 4;
    const int mb   = blockIdx.y * 128;
    const int nb   = blockIdx.x * 128;

    const int arow = t >> 2;
    const int kc8  = (t & 3) * 8;

    const unsigned short* pA0 = &Wb[(size_t)(mb + arow)      * KD + kc8];
    const unsigned short* pA1 = &Wb[(size_t)(mb + arow + 64) * KD + kc8];

    const int n0r = nb + arow, n1r = n0r + 64;
    const int b0 = (n0r >= TC) ? 1 : 0, b1 = (n1r >= TC) ? 1 : 0;
    const int tt0 = n0r - b0 * TC,      tt1 = n1r - b1 * TC;
    const bool hL0 = (tt0 - dil >= 0), hR0 = (tt0 + dil < TC);
    const bool hL1 = (tt1 - dil >= 0), hR1 = (tt1 + dil < TC);
    const unsigned short* pc0 = &Pin[(size_t)n0r * 512 + kc8];
    const unsigned short* pc1 = &Pin[(size_t)n1r * 512 + kc8];
    const long doff = (long)dil * 512;

    f4v acc[4][4];
    #pragma unroll
    for (int a = 0; a < 4; ++a)
        #pragma unroll
        for (int c = 0; c < 4; ++c)
            acc[a][c] = (f4v){0.f, 0.f, 0.f, 0.f};

    constexpr int NSTEP = KD / 32;   // 16
    // prologue: load step-0 raw inputs
    s8v a0 = *(const s8v*)pA0, a1 = *(const s8v*)pA1;
    s8v c0 = *(const s8v*)pc0, c1 = *(const s8v*)pc1;
    s8v l0 = {}, r0 = {}, l1 = {}, r1 = {};
    if (hL0) l0 = *(const s8v*)(pc0 - doff);
    if (hR0) r0 = *(const s8v*)(pc0 + doff);
    if (hL1) l1 = *(const s8v*)(pc1 - doff);
    if (hR1) r1 = *(const s8v*)(pc1 + doff);

    for (int s = 0; s < NSTEP; ++s) {
        const int k0 = s * 32;
        __syncthreads();   // prior iteration's frag reads complete
        *(s8v*)&At[(arow)      * LROW2 + kc8] = a0;
        *(s8v*)&At[(arow + 64) * LROW2 + kc8] = a1;
        {
            s8v ob0, ob1;
            #pragma unroll
            for (int j = 0; j < 8; ++j) {
                const float4 pa = *(const float4*)&dwpL[(size_t)(k0 + kc8 + j) * 8];
                const float4 pb = *(const float4*)&dwpL[(size_t)(k0 + kc8 + j) * 8 + 4];
                float a = bf2f(((const unsigned short*)&c0)[j]) * pa.y;
                if (hL0) a = fmaf(bf2f(((const unsigned short*)&l0)[j]), pa.x, a);
                if (hR0) a = fmaf(bf2f(((const unsigned short*)&r0)[j]), pa.z, a);
                a += pa.w;
                a = (a > 0.f) ? a : pb.w * a;
                a = (a - pb.y) * pb.x + pb.z;
                ((unsigned short*)&ob0)[j] = f2bf(a);
                float e = bf2f(((const unsigned short*)&c1)[j]) * pa.y;
                if (hL1) e = fmaf(bf2f(((const unsigned short*)&l1)[j]), pa.x, e);
                if (hR1) e = fmaf(bf2f(((const unsigned short*)&r1)[j]), pa.z, e);
                e += pa.w;
                e = (e > 0.f) ? e : pb.w * e;
                e = (e - pb.y) * pb.x + pb.z;
                ((unsigned short*)&ob1)[j] = f2bf(e);
            }
            *(s8v*)&Bt[(arow)      * LROW2 + kc8] = ob0;
            *(s8v*)&Bt[(arow + 64) * LROW2 + kc8] = ob1;
        }
        __syncthreads();   // tiles ready

        // prefetch next K-step raw inputs (clamped re-load on last iter)
        const int k0n = ((s + 1 < NSTEP) ? (s + 1) : s) * 32;
        a0 = *(const s8v*)(pA0 + k0n); a1 = *(const s8v*)(pA1 + k0n);
        c0 = *(const s8v*)(pc0 + k0n); c1 = *(const s8v*)(pc1 + k0n);
        if (hL0) l0 = *(const s8v*)(pc0 - doff + k0n);
        if (hR0) r0 = *(const s8v*)(pc0 + doff + k0n);
        if (hL1) l1 = *(const s8v*)(pc1 - doff + k0n);
        if (hR1) r1 = *(const s8v*)(pc1 + doff + k0n);

        s8v av[4], bv[4];
        #pragma unroll
        for (int f = 0; f < 4; ++f) {
            av[f] = *(const s8v*)&At[(wm * 64 + f * 16 + r16) * LROW2 + g * 8];
            bv[f] = *(const s8v*)&Bt[(wn * 64 + f * 16 + r16) * LROW2 + g * 8];
        }
        #pragma unroll
        for (int fm = 0; fm < 4; ++fm)
            #pragma unroll
            for (int fn = 0; fn < 4; ++fn)
                acc[fm][fn] = __builtin_amdgcn_mfma_f32_16x16x32_bf16(
                    av[fm], bv[fn], acc[fm][fn], 0, 0, 0);
    }

    // Epilogue. D frag: col(n) = lane&15, row(m) = (lane>>4)*4 + reg. (verified)
    #pragma unroll
    for (int fm = 0; fm < 4; ++fm) {
        const int mbase = mb + wm * 64 + fm * 16 + g * 4;
        float4 b4 = *(const float4*)&bias[mbase];
        float bb[4] = { b4.x, b4.y, b4.z, b4.w };
        #pragma unroll
        for (int fn = 0; fn < 4; ++fn) {
            const int n = nb + wn * 64 + fn * 16 + r16;
            f4v a = acc[fm][fn];
            u4v rv = {}, ev = {};
            if constexpr (EPI >= 2) rv = *(const u4v*)&Resid[(size_t)n * MOUT + mbase];
            if constexpr (EPI == 3) ev = *(const u4v*)&EncB[(size_t)n * 256 + mbase];
            u4v ro;
            #pragma unroll
            for (int r = 0; r < 4; ++r) {
                float v = a[r] + bb[r];
                if constexpr (EPI >= 2) v += bf2f(rv[r]);
                if constexpr (EPI == 3) {
                    float h  = bf2f(f2bf(v));             // keep old bf16 round-trip
                    float sg = 1.f / (1.f + expf(-h));
                    ro[r] = f2bf(bf2f(ev[r]) * sg);
                } else {
                    ro[r] = f2bf(v);
                }
            }
            *(u4v*)&OutB[(size_t)n * MOUT + mbase] = ro;
        }
    }
}

// =====================================================================
// Decoder on bf16 [N][E] (verified incl. r9 coverage fix)
// =====================================================================
__global__ __launch_bounds__(256)
void decoder_k(const unsigned short* __restrict__ Mb,
               const float* __restrict__ dec_w, const float* __restrict__ db,
               float* __restrict__ out)
{
    __shared__ float wlds[5120];        // [256 e][20 k]
    __shared__ float red[2560];         // [32 t0][8 grp][10 j]
    const int t = threadIdx.x;
    #pragma unroll
    for (int i = 0; i < 5; ++i)
        ((float4*)wlds)[t + i * 256] = ((const float4*)dec_w)[t + i * 256];
    __syncthreads();

    const int grp = t >> 5;             // 0..7
    const int t0l = t & 31;
    const int t0  = blockIdx.x * 32 + t0l;
    const int by  = blockIdx.y;
    const int n0  = by * TC + t0 + 2;
    const int e0  = grp * 32;

    float acc[10];
    #pragma unroll
    for (int j = 0; j < 10; ++j) acc[j] = 0.f;

    #pragma unroll
    for (int q = 0; q < 4; ++q) {
        u8v a0 = *(const u8v*)&Mb[(size_t)n0 * 256 + e0 + q * 8];
        u8v a1 = *(const u8v*)&Mb[(size_t)(n0 - 1) * 256 + e0 + q * 8];
        #pragma unroll
        for (int i = 0; i < 8; ++i) {
            float m0 = bf2f(a0[i]);
            float m1 = bf2f(a1[i]);
            const float* wr = &wlds[(e0 + q * 8 + i) * 20];
            #pragma unroll
            for (int j = 0; j < 10; ++j)
                acc[j] = fmaf(m0, wr[j], fmaf(m1, wr[j + 10], acc[j]));
        }
    }
    #pragma unroll
    for (int j = 0; j < 10; ++j)
        red[(t0l * 8 + grp) * 10 + j] = acc[j];
    __syncthreads();

    for (int s = t; s < 320; s += 256) {          // full coverage (r9 fix)
        int t0l2 = s / 10, j = s - t0l2 * 10;
        float sm = 0.f;
        #pragma unroll
        for (int gq = 0; gq < 8; ++gq) sm += red[(t0l2 * 8 + gq) * 10 + j];
        out[(size_t)by * TLEN + (size_t)(blockIdx.x * 32 + t0l2) * 10 + j] = sm + db[0];
    }
}

// =====================================================================
extern "C" void kernel_launch(void* const* d_in, const int* in_sizes, int n_in,
                              void* d_out, int out_size, void* d_ws, size_t ws_size,
                              hipStream_t stream)
{
    (void)in_sizes; (void)n_in; (void)out_size; (void)ws_size;
    const float* x     = (const float*)d_in[0];
    const float* enc_w = (const float*)d_in[1];
    const float* enc_b = (const float*)d_in[2];
    const float* w1    = (const float*)d_in[3];
    const float* b1    = (const float*)d_in[4];
    const float* a1    = (const float*)d_in[5];
    const float* g1    = (const float*)d_in[6];
    const float* be1   = (const float*)d_in[7];
    const float* m1    = (const float*)d_in[8];
    const float* v1    = (const float*)d_in[9];
    const float* wd    = (const float*)d_in[10];
    const float* bd    = (const float*)d_in[11];
    const float* a2    = (const float*)d_in[12];
    const float* g2    = (const float*)d_in[13];
    const float* be2   = (const float*)d_in[14];
    const float* m2    = (const float*)d_in[15];
    const float* v2    = (const float*)d_in[16];
    const float* w2    = (const float*)d_in[17];
    const float* b2    = (const float*)d_in[18];
    const float* dec_w = (const float*)d_in[19];
    const float* dec_b = (const float*)d_in[20];
    float* out = (float*)d_out;

    // ---- workspace carve-up ----
    const size_t B_EN = (size_t)NS * 256 * 2;      //  6,619,136
    const size_t B_DN = (size_t)NS * 512 * 2;      // 13,238,272
    char* p = (char*)d_ws;
    unsigned short* Hb   = (unsigned short*)p;  p += B_EN;   // block input / residual
    unsigned short* Hb2  = (unsigned short*)p;  p += B_EN;   // intra-block H
    unsigned short* EncB = (unsigned short*)p;  p += B_EN;
    unsigned short* Pb   = (unsigned short*)p;  p += B_DN;
    unsigned short* Qb   = (unsigned short*)p;  p += B_DN;   // now only used as Mb
    unsigned short* w1b  = (unsigned short*)p;  p += (size_t)12*512*256*2;
    unsigned short* w2b  = (unsigned short*)p;  p += (size_t)12*512*256*2;
    float*          dwp  = (float*)p;                        // 12*512*8 floats
    unsigned short* Mb   = Qb;

    dim3 blk(256);
    wcvt_k<<<dim3(NB0 + 24), blk, 0, stream>>>(w1, w2, wd, bd, a2, g2, be2, m2, v2,
                                               w1b, w2b, dwp);
    encoder_k<<<dim3(101, 2), blk, 0, stream>>>(x, enc_w, enc_b, EncB, Hb);

    for (int bI = 0; bI < NBLK; ++bI) {
        for (int i = 0; i < NLAY; ++i) {
            const int li  = bI * NLAY + i;
            const int dil = 1 << i;
            // conv1: E->D (bias+PReLU+BN); layer0 reads block input Hb, else Hb2
            const unsigned short* hin = (i == 0) ? Hb : Hb2;
            gemm_bf16_k<ECH, DCH><<<dim3(NTILE, DCH / 128), blk, 0, stream>>>(
                w1b + (size_t)li * DCH * ECH, hin, Pb,
                b1 + (size_t)li * DCH, a1 + li,
                g1 + (size_t)li * DCH, be1 + (size_t)li * DCH,
                m1 + (size_t)li * DCH, v1 + (size_t)li * DCH);
            // conv2 with dw FUSED into B-staging
            const float* dwpL = dwp + (size_t)li * 512 * 8;
            const unsigned short* wL = w2b + (size_t)li * ECH * DCH;
            const float* bL = b2 + (size_t)li * ECH;
            if (li == NBLK * NLAY - 1) {          // final: +resid +mask -> Mb
                gemm_dw_k<3><<<dim3(NTILE, ECH / 128), blk, 0, stream>>>(
                    wL, Pb, dwpL, Mb, bL, Hb, EncB, dil);
            } else if (i == NLAY - 1) {           // block end: +resid -> Hb in place
                gemm_dw_k<2><<<dim3(NTILE, ECH / 128), blk, 0, stream>>>(
                    wL, Pb, dwpL, Hb, bL, Hb, nullptr, dil);
            } else {                              // mid: bias only -> Hb2
                gemm_dw_k<1><<<dim3(NTILE, ECH / 128), blk, 0, stream>>>(
                    wL, Pb, dwpL, Hb2, bL, nullptr, nullptr, dil);
            }
        }
    }

    decoder_k<<<dim3(200, 2), blk, 0, stream>>>(Mb, dec_w, dec_b, out);
}